// Round 7
// baseline (357.120 us; speedup 1.0000x reference)
//
#include <hip/hip_runtime.h>
#include <hip/hip_bf16.h>

#define B_   4
#define S_   2048
#define D_   1024
#define H_   16
#define DH_  64
#define M_   (B_ * S_)

typedef __attribute__((ext_vector_type(8))) short  bfrag8;   // 8 bf16 = 4 VGPRs
typedef __attribute__((ext_vector_type(4))) float  facc4;    // 4 fp32 accum
typedef unsigned short u16;
typedef unsigned long long u64;

__device__ __forceinline__ u16 f2bf(float f) {
    union { __hip_bfloat16 h; u16 u; } c;
    c.h = __float2bfloat16(f);
    return c.u;
}

// manual RNE fp32->bf16 (finite inputs only)
__device__ __forceinline__ u16 bfr(float f) {
    unsigned b = __float_as_uint(f);
    return (u16)((b + 0x7FFFu + ((b >> 16) & 1u)) >> 16);
}

// async global->LDS, 16B per lane; LDS dest must be wave-uniform base + lane*16
__device__ __forceinline__ void gl_lds16(const u16* g, u16* l) {
    __builtin_amdgcn_global_load_lds((const __attribute__((address_space(1))) void*)g,
                                     (__attribute__((address_space(3))) void*)l,
                                     16, 0, 0);
}

// ---------------------------------------------------------------------------
// fp32 -> bf16 elementwise convert (x)
// ---------------------------------------------------------------------------
__global__ __launch_bounds__(256) void cvt_x(const float* __restrict__ x,
                                             u16* __restrict__ o, int n) {
    int i = (blockIdx.x * 256 + threadIdx.x) * 4;
    if (i >= n) return;
    float4 v = *(const float4*)(x + i);
    ushort4 r;
    r.x = f2bf(v.x); r.y = f2bf(v.y); r.z = f2bf(v.z); r.w = f2bf(v.w);
    *(ushort4*)(o + i) = r;
}

// ---------------------------------------------------------------------------
// fp32 W[k][n] -> bf16 WT[n][k] transpose+convert, 32x32 LDS tiles.
// ---------------------------------------------------------------------------
__global__ __launch_bounds__(256) void cvt_wt(const float* __restrict__ w0, const float* __restrict__ w1,
                                              const float* __restrict__ w2, const float* __restrict__ w3,
                                              u16* __restrict__ o0, u16* __restrict__ o1,
                                              u16* __restrict__ o2, u16* __restrict__ o3) {
    const float* w; u16* o;
    switch (blockIdx.z) {
        case 0: w = w0; o = o0; break;
        case 1: w = w1; o = o1; break;
        case 2: w = w2; o = o2; break;
        default: w = w3; o = o3; break;
    }
    __shared__ u16 t[32][33];
    int kb = blockIdx.x * 32, nb = blockIdx.y * 32;
    int c = threadIdx.x & 31, r0 = threadIdx.x >> 5;
#pragma unroll
    for (int i = 0; i < 4; i++) {
        int r = r0 + 8 * i;
        t[r][c] = f2bf(w[(kb + r) * D_ + nb + c]);
    }
    __syncthreads();
#pragma unroll
    for (int i = 0; i < 4; i++) {
        int r = r0 + 8 * i;
        o[(nb + r) * D_ + kb + c] = t[c][r];
    }
}

// ---------------------------------------------------------------------------
// m97-style GEMM body: C = (A @ BT^T + bias) [* scale]. 128x128 tile, BK=32,
// global_load_lds 16B staging, XOR chunk swizzle.
//   mode 0: bf16 -> [B,H,S,DH]          (Q, K; bias by col)
//   mode 2: fp32 -> [M,N] row-major      (output projection; bias by col)
//   mode 3: bf16 -> [row][col] row-major, row-stride M_ (transposed V-GEMM:
//           A=WTv rows=out features, BT=X16 cols=tokens; bias by ROW)
// ---------------------------------------------------------------------------
__device__ __forceinline__ void gemm_body(const u16* __restrict__ A,
                                          const u16* __restrict__ BT,
                                          const float* __restrict__ bias,
                                          void* __restrict__ Cout, int mode, float scale,
                                          u16* As, u16* Bs) {
    int tid = threadIdx.x;
    int nb = blockIdx.x * 128, mb = blockIdx.y * 128;
    int w = tid >> 6, lane = tid & 63, quad = lane >> 4, l16 = lane & 15;
    int wm = (w >> 1) * 64, wn = (w & 1) * 64;

    int c0 = tid, c1 = tid + 256;
    int row0 = c0 >> 2, row1 = c1 >> 2;
    int sw0 = (c0 & 3) ^ ((row0 >> 2) & 3);
    int sw1 = (c1 & 3) ^ ((row1 >> 2) & 3);
    const u16* Ag0 = A + (mb + row0) * D_ + sw0 * 8;
    const u16* Ag1 = A + (mb + row1) * D_ + sw1 * 8;
    const u16* Bg0 = BT + (nb + row0) * D_ + sw0 * 8;
    const u16* Bg1 = BT + (nb + row1) * D_ + sw1 * 8;
    u16* Al0 = As + c0 * 8; u16* Al1 = As + c1 * 8;
    u16* Bl0 = Bs + c0 * 8; u16* Bl1 = Bs + c1 * 8;

    int swr = (l16 >> 2) & 3;

    facc4 acc[4][4] = {};
    for (int kk = 0; kk < D_; kk += 32) {
        __syncthreads();
        gl_lds16(Ag0 + kk, Al0);
        gl_lds16(Ag1 + kk, Al1);
        gl_lds16(Bg0 + kk, Bl0);
        gl_lds16(Bg1 + kk, Bl1);
        __syncthreads();

        bfrag8 af[4], bf[4];
#pragma unroll
        for (int mt = 0; mt < 4; ++mt)
            af[mt] = *(const bfrag8*)(As + (wm + mt * 16 + l16) * 32 + ((quad ^ swr) << 3));
#pragma unroll
        for (int nt = 0; nt < 4; ++nt)
            bf[nt] = *(const bfrag8*)(Bs + (wn + nt * 16 + l16) * 32 + ((quad ^ swr) << 3));
#pragma unroll
        for (int mt = 0; mt < 4; ++mt)
#pragma unroll
            for (int nt = 0; nt < 4; ++nt)
                acc[mt][nt] = __builtin_amdgcn_mfma_f32_16x16x32_bf16(af[mt], bf[nt], acc[mt][nt], 0, 0, 0);
    }

#pragma unroll
    for (int mt = 0; mt < 4; ++mt) {
        int m_base = mb + wm + mt * 16 + quad * 4;
        if (mode == 3) {
            float bvr[4];
#pragma unroll
            for (int r = 0; r < 4; ++r) bvr[r] = bias[m_base + r];
#pragma unroll
            for (int nt = 0; nt < 4; ++nt) {
                int n = nb + wn + nt * 16 + l16;
#pragma unroll
                for (int r = 0; r < 4; ++r)
                    ((u16*)Cout)[(size_t)(m_base + r) * M_ + n] = bfr(acc[mt][nt][r] + bvr[r]);
            }
        } else {
#pragma unroll
            for (int nt = 0; nt < 4; ++nt) {
                int n = nb + wn + nt * 16 + l16;
                float bv = bias[n];
                int h = n >> 6, dd = n & 63;
#pragma unroll
                for (int r = 0; r < 4; ++r) {
                    int m = m_base + r;
                    float v = (acc[mt][nt][r] + bv) * scale;
                    int bi = m >> 11, s = m & (S_ - 1);
                    if (mode == 0) {
                        ((u16*)Cout)[(((bi * H_ + h) * S_) + s) * DH_ + dd] = bfr(v);
                    } else {
                        ((float*)Cout)[(size_t)m * D_ + n] = v;
                    }
                }
            }
        }
    }
}

#define CE_Q 0.18033688011112042f   // log2(e)/sqrt(DH), folded into Q

__global__ __launch_bounds__(256) void gemm_qk(const u16* __restrict__ A,
                                               const u16* __restrict__ WTq, const float* __restrict__ bq, u16* __restrict__ Qb,
                                               const u16* __restrict__ WTk, const float* __restrict__ bk, u16* __restrict__ Kb) {
    __shared__ u16 As[128 * 32];
    __shared__ u16 Bs[128 * 32];
    if (blockIdx.z == 0) gemm_body(A, WTq, bq, Qb, 0, CE_Q, As, Bs);   // Q pre-scaled
    else                 gemm_body(A, WTk, bk, Kb, 0, 1.0f, As, Bs);
}

// V^T = Wv^T @ X^T computed directly: A=WTv (1024 rows), BT=X16 (8192 rows)
__global__ __launch_bounds__(256) void gemm_v(const u16* __restrict__ WTv,
                                              const u16* __restrict__ X,
                                              const float* __restrict__ bv,
                                              u16* __restrict__ VTb) {
    __shared__ u16 As[128 * 32];
    __shared__ u16 Bs[128 * 32];
    gemm_body(WTv, X, bv, VTb, 3, 1.0f, As, Bs);
}

__global__ __launch_bounds__(256) void gemm_o(const u16* __restrict__ A,
                                              const u16* __restrict__ WTo, const float* __restrict__ bo,
                                              float* __restrict__ out) {
    __shared__ u16 As[128 * 32];
    __shared__ u16 Bs[128 * 32];
    gemm_body(A, WTo, bo, out, 2, 1.0f, As, Bs);
}

// ---------------------------------------------------------------------------
// Flash attention, S^T/O^T, fixed-base softmax, split-K across wave pairs.
// Block = 4 waves = 2 chunk-pairs. Pair pr = w>>1 handles chunks u=bx*2+pr
// and 63-u (32 q-rows each); within the pair, wave sub=w&1 does tiles
// t ≡ sub (mod 2). Partials (O^T fp32, l) combine by ADDITION (fixed base:
// no max reconciliation) through per-pair LDS; 2 barriers per chunk.
// 1024 blocks, lb(256,4) -> 16 waves/CU. V^T row stride = M_ (transposed
// V-GEMM layout). K/mask prefetched one owned-tile (64 keys) ahead.
// ---------------------------------------------------------------------------
// exp2 + pack + lane-transpose (bpermute) + PV accumulate for one q-tile
__device__ __forceinline__ void soft_pv(const float* p, float& lp, facc4* oaccq,
                                        const bfrag8* vf, int a0, int a1, bool qlo) {
    float rs = 0.f;
    unsigned pk[4];
#pragma unroll
    for (int j = 0; j < 4; ++j) {
        float e0 = exp2f(p[2 * j]);
        float e1 = exp2f(p[2 * j + 1]);
        rs += e0; rs += e1;
        pk[j] = __builtin_amdgcn_perm(__float_as_uint(e1), __float_as_uint(e0), 0x07060302u);
    }
    lp += rs;
    union { unsigned d[4]; bfrag8 v; } pb;
    {
        unsigned lo, hi;
        lo = __builtin_amdgcn_ds_bpermute(a0, (int)pk[0]);
        hi = __builtin_amdgcn_ds_bpermute(a0, (int)pk[2]);
        pb.d[0] = qlo ? lo : hi;
        lo = __builtin_amdgcn_ds_bpermute(a0, (int)pk[1]);
        hi = __builtin_amdgcn_ds_bpermute(a0, (int)pk[3]);
        pb.d[1] = qlo ? lo : hi;
        lo = __builtin_amdgcn_ds_bpermute(a1, (int)pk[0]);
        hi = __builtin_amdgcn_ds_bpermute(a1, (int)pk[2]);
        pb.d[2] = qlo ? lo : hi;
        lo = __builtin_amdgcn_ds_bpermute(a1, (int)pk[1]);
        hi = __builtin_amdgcn_ds_bpermute(a1, (int)pk[3]);
        pb.d[3] = qlo ? lo : hi;
    }
#pragma unroll
    for (int dt = 0; dt < 4; ++dt)
        oaccq[dt] = __builtin_amdgcn_mfma_f32_16x16x32_bf16(vf[dt], pb.v, oaccq[dt], 0, 0, 0);
}

#define OBS 68   // obuf fp32 row stride (q rows of 64 d + 4 pad)

__global__ __launch_bounds__(256, 4) void attn(const u16* __restrict__ Q,
                                               const u16* __restrict__ K,
                                               const u16* __restrict__ VT,
                                               const int* __restrict__ pm,
                                               u16* __restrict__ Aout) {
    int h = blockIdx.y, b = blockIdx.z;
    int tid = threadIdx.x, w = tid >> 6, lane = tid & 63;
    int quad = lane >> 4, l16 = lane & 15;
    int pr = w >> 1, sub = w & 1;

    __shared__ float obuf[2][32 * OBS];
    __shared__ float lbuf[2][2][16];

    const u16* Qp = Q + (size_t)(b * H_ + h) * S_ * DH_;
    const u16* Kp = K + (size_t)(b * H_ + h) * S_ * DH_;
    const u16* Vp = VT + (size_t)h * DH_ * M_ + b * S_;   // row stride M_
    const int* pmb = pm + b * S_;
    u16* Ao = Aout + (size_t)b * S_ * D_ + h * DH_;

    int u = blockIdx.x * 2 + pr;                // 0..31  (grid.x = 16)

    int a0 = ((((2 * quad) & 3) * 16 + l16) << 2);
    int a1 = ((((2 * quad + 1) & 3) * 16 + l16) << 2);
    bool qlo = quad < 2;

    for (int half = 0; half < 2; ++half) {
        int c = half ? 63 - u : u;              // chunk 0..63 (32 q-rows)
        int qw = c * 32;

        bfrag8 qf[2][2];
#pragma unroll
        for (int qt = 0; qt < 2; ++qt)
#pragma unroll
            for (int cc = 0; cc < 2; ++cc)
                qf[qt][cc] = *(const bfrag8*)(Qp + (qw + qt * 16 + l16) * DH_ + cc * 32 + quad * 8);

        facc4 oacc[2][4] = {};                  // O^T partial: [qt][dt]
        float lp[2] = {0.f, 0.f};

        int t = sub;
        bfrag8 kn[4]; int pn = 0;
        if (t <= c) {
            int k0 = t * 32;
            kn[0] = *(const bfrag8*)(Kp + (k0 + l16) * DH_ + quad * 8);
            kn[1] = *(const bfrag8*)(Kp + (k0 + l16) * DH_ + 32 + quad * 8);
            kn[2] = *(const bfrag8*)(Kp + (k0 + 16 + l16) * DH_ + quad * 8);
            kn[3] = *(const bfrag8*)(Kp + (k0 + 16 + l16) * DH_ + 32 + quad * 8);
            pn = pmb[k0 + (lane & 31)];
        }
        for (; t <= c; t += 2) {
            int k0 = t * 32;
            bfrag8 kf00 = kn[0], kf01 = kn[1], kf10 = kn[2], kf11 = kn[3];
            int cpm = pn;
            if (t + 2 <= c) {                   // prefetch next owned tile (+64 keys)
                int k1 = k0 + 64;
                kn[0] = *(const bfrag8*)(Kp + (k1 + l16) * DH_ + quad * 8);
                kn[1] = *(const bfrag8*)(Kp + (k1 + l16) * DH_ + 32 + quad * 8);
                kn[2] = *(const bfrag8*)(Kp + (k1 + 16 + l16) * DH_ + quad * 8);
                kn[3] = *(const bfrag8*)(Kp + (k1 + 16 + l16) * DH_ + 32 + quad * 8);
                pn = pmb[k1 + (lane & 31)];
            }
            bfrag8 vf[4];
#pragma unroll
            for (int dt = 0; dt < 4; ++dt)
                vf[dt] = *(const bfrag8*)(Vp + (size_t)(dt * 16 + l16) * M_ + k0 + quad * 8);

            facc4 st[2][2] = {};                // S^T (pre-scaled): row=key, col=q
#pragma unroll
            for (int qt = 0; qt < 2; ++qt) {
                st[qt][0] = __builtin_amdgcn_mfma_f32_16x16x32_bf16(kf00, qf[qt][0], st[qt][0], 0, 0, 0);
                st[qt][0] = __builtin_amdgcn_mfma_f32_16x16x32_bf16(kf01, qf[qt][1], st[qt][0], 0, 0, 0);
                st[qt][1] = __builtin_amdgcn_mfma_f32_16x16x32_bf16(kf10, qf[qt][0], st[qt][1], 0, 0, 0);
                st[qt][1] = __builtin_amdgcn_mfma_f32_16x16x32_bf16(kf11, qf[qt][1], st[qt][1], 0, 0, 0);
            }

            unsigned vm = (unsigned)__ballot(cpm != 0 && lane < 32);

            if (vm == 0xffffffffu && t < c) {
#pragma unroll
                for (int qt = 0; qt < 2; ++qt) {
                    float p[8];
#pragma unroll
                    for (int kt = 0; kt < 2; ++kt)
#pragma unroll
                        for (int r = 0; r < 4; ++r) p[kt * 4 + r] = st[qt][kt][r];
                    soft_pv(p, lp[qt], oacc[qt], vf, a0, a1, qlo);
                }
            } else {
#pragma unroll
                for (int qt = 0; qt < 2; ++qt) {
                    int q0 = qw + qt * 16;
                    float p[8];
#pragma unroll
                    for (int kt = 0; kt < 2; ++kt)
#pragma unroll
                        for (int r = 0; r < 4; ++r) {
                            int kl = kt * 16 + quad * 4 + r;
                            bool ok = ((vm >> kl) & 1u) && (k0 + kl <= q0 + l16);
                            p[kt * 4 + r] = ok ? st[qt][kt][r] : -1e30f;
                        }
                    soft_pv(p, lp[qt], oacc[qt], vf, a0, a1, qlo);
                }
            }
        }

        // per-wave l reduce across quads
        float lw[2];
#pragma unroll
        for (int qt = 0; qt < 2; ++qt) {
            float l = lp[qt];
            l += __shfl_xor(l, 16);
            l += __shfl_xor(l, 32);
            lw[qt] = l;
        }

        // combine partials through per-pair LDS
        if (sub == 0) {
#pragma unroll
            for (int qt = 0; qt < 2; ++qt) {
#pragma unroll
                for (int dt = 0; dt < 4; ++dt)
                    *(facc4*)(&obuf[pr][(qt * 16 + l16) * OBS + dt * 16 + quad * 4]) = oacc[qt][dt];
                if (quad == 0) lbuf[pr][qt][l16] = lw[qt];
            }
        }
        __syncthreads();
        if (sub == 1) {
#pragma unroll
            for (int qt = 0; qt < 2; ++qt) {
                float l = lw[qt] + lbuf[pr][qt][l16];
                float linv = (l > 0.f) ? 1.f / l : 0.f;
                size_t qoff = (size_t)(qw + qt * 16 + l16) * D_;
#pragma unroll
                for (int dt = 0; dt < 4; ++dt) {
                    facc4 o = oacc[qt][dt] + *(const facc4*)(&obuf[pr][(qt * 16 + l16) * OBS + dt * 16 + quad * 4]);
                    union { u16 hh[4]; u64 q; } pk4;
#pragma unroll
                    for (int r = 0; r < 4; ++r) pk4.hh[r] = bfr(o[r] * linv);
                    *(u64*)(Ao + qoff + dt * 16 + quad * 4) = pk4.q;
                }
            }
        }
        __syncthreads();
    }
}

// ---------------------------------------------------------------------------
extern "C" void kernel_launch(void* const* d_in, const int* in_sizes, int n_in,
                              void* d_out, int out_size, void* d_ws, size_t ws_size,
                              hipStream_t stream) {
    const float* x  = (const float*)d_in[0];
    const float* Wq = (const float*)d_in[1];
    const float* bq = (const float*)d_in[2];
    const float* Wk = (const float*)d_in[3];
    const float* bk = (const float*)d_in[4];
    const float* Wv = (const float*)d_in[5];
    const float* bv = (const float*)d_in[6];
    const float* Wo = (const float*)d_in[7];
    const float* bo = (const float*)d_in[8];
    const int*   pm = (const int*)d_in[9];
    float* out = (float*)d_out;

    char* ws = (char*)d_ws;
    const size_t SZ_XD = (size_t)M_ * D_ * 2;   // 16 MiB bf16
    const size_t SZ_W  = (size_t)D_ * D_ * 2;   //  2 MiB bf16
    u16* X16 = (u16*)ws;                 // reused as attended output (safe: X16's
                                         // last read is gemm_v; attn writes later)
    u16* WTq = (u16*)(ws + SZ_XD);
    u16* WTk = (u16*)(ws + SZ_XD + SZ_W);
    u16* WTv = (u16*)(ws + SZ_XD + 2 * SZ_W);
    u16* WTo = (u16*)(ws + SZ_XD + 3 * SZ_W);
    u16* Qb  = (u16*)(ws + SZ_XD + 4 * SZ_W);
    u16* Kb  = (u16*)(ws + 2 * SZ_XD + 4 * SZ_W);
    u16* VTb = (u16*)(ws + 3 * SZ_XD + 4 * SZ_W);  // [1024][8192] bf16
    u16* Att = X16;

    cvt_x<<<(M_ * D_) / (256 * 4), 256, 0, stream>>>(x, X16, M_ * D_);
    cvt_wt<<<dim3(D_ / 32, D_ / 32, 4), 256, 0, stream>>>(Wq, Wk, Wv, Wo, WTq, WTk, WTv, WTo);

    gemm_qk<<<dim3(D_ / 128, M_ / 128, 2), 256, 0, stream>>>(X16, WTq, bq, Qb, WTk, bk, Kb);
    gemm_v<<<dim3(M_ / 128, D_ / 128), 256, 0, stream>>>(WTv, X16, bv, VTb);

    attn<<<dim3(16, H_, B_), 256, 0, stream>>>(Qb, Kb, VTb, pm, Att);

    gemm_o<<<dim3(D_ / 128, M_ / 128), 256, 0, stream>>>(Att, WTo, bo, out);
}